// Round 2
// baseline (95.955 us; speedup 1.0000x reference)
//
#include <hip/hip_runtime.h>
#include <hip/hip_bf16.h>
#include <stdint.h>

// Problem: B=4, N=1024, D=512, F=16, O=64, V=64. ALL float tensors are fp32
// (reference dtype; round-1 NaN proved they are not bf16). idx is int32.
// out[b,n,f,o] = sum_d (x[b,n,d]+bias[v,d])*W[v,d,o], v=idx[b,f]
//             = (x[b] @ W[v])[n,o] + c[v][o],  c[v][o]=sum_d bias[v,d]*W[v,d,o]
// Strategy: convert x,W to bf16 once (prep), run MFMA GEMM, add fp32 c[v] in
// epilogue. Error ~0.04 vs threshold 0.145 (2% of max|ref|).

typedef __bf16 bf16_t;
typedef __bf16 bf16x8 __attribute__((ext_vector_type(8)));
typedef float floatx4 __attribute__((ext_vector_type(4)));

__device__ __forceinline__ void async_ld16(const bf16_t* g, bf16_t* l) {
    __builtin_amdgcn_global_load_lds(
        (const __attribute__((address_space(1))) void*)g,
        (__attribute__((address_space(3))) void*)l,
        16, 0, 0);
}

// ---------------------------------------------------------------------------
// Prep: blocks [0,64): per-v W transpose fp32->bf16 Wt[v][o][d] + c[v][o] fp32.
//       blocks [64,1088): x fp32 -> bf16 (2048 elements per block).
// ---------------------------------------------------------------------------
__global__ __launch_bounds__(256) void prep_kernel(
    const float* __restrict__ w,     // [64][512][64]
    const float* __restrict__ bias,  // [64][512]
    const float* __restrict__ x,     // [4096][512]
    bf16_t* __restrict__ wt,         // [64][64][512]
    float* __restrict__ cv,          // [64][64]
    bf16_t* __restrict__ xb)         // [4096][512]
{
    const int t = threadIdx.x;
    if (blockIdx.x >= 64) {
        const int base = (blockIdx.x - 64) * 2048 + t * 8;
        const float4 f0 = *(const float4*)(x + base);
        const float4 f1 = *(const float4*)(x + base + 4);
        bf16x8 o;
        o[0] = (bf16_t)f0.x; o[1] = (bf16_t)f0.y;
        o[2] = (bf16_t)f0.z; o[3] = (bf16_t)f0.w;
        o[4] = (bf16_t)f1.x; o[5] = (bf16_t)f1.y;
        o[6] = (bf16_t)f1.z; o[7] = (bf16_t)f1.w;
        *(bf16x8*)(xb + base) = o;
        return;
    }

    const int v = blockIdx.x;
    __shared__ float tile[64][68];   // stride 68: 16B-aligned float4 rows
    __shared__ float bch[64];
    __shared__ float red[4][64];

    const int r  = t >> 2, cs = (t & 3) * 16;  // load map
    const int o  = t >> 2, ds = (t & 3) * 16;  // transpose-store map
    const int dq = t >> 6, oc = t & 63;        // c-reduction map
    float csum = 0.f;

    for (int c = 0; c < 8; ++c) {
        __syncthreads();  // previous chunk consumers done
        const float* src = w + (size_t)v * 32768 + (size_t)(c * 64 + r) * 64 + cs;
        *(float4*)&tile[r][cs]      = *(const float4*)(src);
        *(float4*)&tile[r][cs + 4]  = *(const float4*)(src + 4);
        *(float4*)&tile[r][cs + 8]  = *(const float4*)(src + 8);
        *(float4*)&tile[r][cs + 12] = *(const float4*)(src + 12);
        if (t < 64) bch[t] = bias[v * 512 + c * 64 + t];
        __syncthreads();

        // Transposed bf16 write: row o, 16 consecutive d.
        bf16x8 t0, t1;
#pragma unroll
        for (int j = 0; j < 8; ++j) t0[j] = (bf16_t)tile[ds + j][o];
#pragma unroll
        for (int j = 0; j < 8; ++j) t1[j] = (bf16_t)tile[ds + 8 + j][o];
        bf16_t* dst = wt + ((size_t)v * 64 + o) * 512 + c * 64 + ds;
        *(bf16x8*)&dst[0] = t0;
        *(bf16x8*)&dst[8] = t1;

        // fp32 partial c[v][oc] over this chunk's 16 rows (dq*16..+16).
#pragma unroll
        for (int j = 0; j < 16; ++j) {
            const int dl = dq * 16 + j;
            csum += bch[dl] * tile[dl][oc];
        }
    }
    red[dq][oc] = csum;
    __syncthreads();
    if (t < 64) cv[v * 64 + t] = red[0][t] + red[1][t] + red[2][t] + red[3][t];
}

// ---------------------------------------------------------------------------
// GEMM: block = (b, mtile of 128 rows, f). BM=128, BN=64, BK=32, 256 threads
// = 4 waves, each 64x32 = 4x2 frags of 16x16x32 bf16 MFMA. Double-buffered
// LDS, staging via global_load_lds width 16. fp32 output + c[v] epilogue.
// ---------------------------------------------------------------------------
__global__ __launch_bounds__(256, 2) void gemm_kernel(
    const bf16_t* __restrict__ xb,   // [4096][512]
    const bf16_t* __restrict__ wt,   // [64][64][512]
    const float*  __restrict__ cv,   // [64][64]
    const int*    __restrict__ idx,  // [4][16]
    float* __restrict__ out)         // [4096][1024], col = f*64+o
{
    const int bid = blockIdx.x;
    const int f  = bid & 15;
    const int mt = (bid >> 4) & 7;
    const int b  = bid >> 7;
    const int v  = idx[b * 16 + f];

    const int tid  = threadIdx.x;
    const int lane = tid & 63;
    const int wave = tid >> 6;
    const int wm = wave >> 1;
    const int wn = wave & 1;
    const int l15 = lane & 15;
    const int l4  = lane >> 4;

    const bf16_t* Ag = xb + (size_t)(b * 1024 + mt * 128) * 512;  // [128][512]
    const bf16_t* Bg = wt + (size_t)v * 64 * 512;                 // [64][512]

    __shared__ __align__(16) bf16_t As[2][128 * 32];  // 8KB each
    __shared__ __align__(16) bf16_t Bs[2][64 * 32];   // 4KB each

    floatx4 acc[4][2] = {};

    // A: 512 segs of 16B (row=s>>2, q=s&3), threads handle s=tid, s=tid+256.
    // B: 256 segs of 16B (row=s>>2, q=s&3), s=tid.   LDS dest = s*16 bytes.
    const int ar0 = tid >> 2;
    const int ar1 = (tid + 256) >> 2;
    const int aq  = (tid & 3) * 8;
    const int br  = tid >> 2;          // FIXED (was tid>>1: OOB rows)
    const int bq  = (tid & 3) * 8;

    async_ld16(Ag + ar0 * 512 + aq, &As[0][tid * 8]);
    async_ld16(Ag + ar1 * 512 + aq, &As[0][(tid + 256) * 8]);
    async_ld16(Bg + br * 512 + bq, &Bs[0][tid * 8]);

    for (int kk = 0; kk < 16; ++kk) {
        const int buf = kk & 1;
        __syncthreads();  // drains vmcnt: buf ready; reads of buf^1 complete
        if (kk < 15) {
            const int k0 = (kk + 1) * 32;
            async_ld16(Ag + ar0 * 512 + k0 + aq, &As[buf ^ 1][tid * 8]);
            async_ld16(Ag + ar1 * 512 + k0 + aq, &As[buf ^ 1][(tid + 256) * 8]);
            async_ld16(Bg + br * 512 + k0 + bq, &Bs[buf ^ 1][tid * 8]);
        }
        bf16x8 a[4], bb[2];
#pragma unroll
        for (int mi = 0; mi < 4; ++mi)
            a[mi] = *(const bf16x8*)&As[buf][(wm * 64 + mi * 16 + l15) * 32 + l4 * 8];
#pragma unroll
        for (int ni = 0; ni < 2; ++ni)
            bb[ni] = *(const bf16x8*)&Bs[buf][(wn * 32 + ni * 16 + l15) * 32 + l4 * 8];
#pragma unroll
        for (int mi = 0; mi < 4; ++mi)
#pragma unroll
            for (int ni = 0; ni < 2; ++ni)
                acc[mi][ni] = __builtin_amdgcn_mfma_f32_16x16x32_bf16(
                    a[mi], bb[ni], acc[mi][ni], 0, 0, 0);
    }

    // Epilogue: C layout col = lane&15, row = (lane>>4)*4 + r. fp32 out + c[v].
    const int colbase = wn * 32 + l15;
    const float c0 = cv[v * 64 + colbase];
    const float c1 = cv[v * 64 + colbase + 16];
    float* outp = out + (size_t)(b * 1024 + mt * 128 + wm * 64 + l4 * 4) * 1024
                      + f * 64;
#pragma unroll
    for (int mi = 0; mi < 4; ++mi) {
#pragma unroll
        for (int r = 0; r < 4; ++r) {
            float* row = outp + (size_t)(mi * 16 + r) * 1024;
            row[colbase]      = acc[mi][0][r] + c0;
            row[colbase + 16] = acc[mi][1][r] + c1;
        }
    }
}

// ---------------------------------------------------------------------------
// Fallback (ws too small): direct fp32, slow but correct.
// ---------------------------------------------------------------------------
__global__ __launch_bounds__(256) void naive_kernel(
    const float* __restrict__ x, const float* __restrict__ w,
    const float* __restrict__ bias, const int* __restrict__ idx,
    float* __restrict__ out)
{
    const int b = blockIdx.x >> 10;
    const int n = blockIdx.x & 1023;
    __shared__ float xr[512];
    for (int d = threadIdx.x; d < 512; d += 256)
        xr[d] = x[(size_t)(b * 1024 + n) * 512 + d];
    __syncthreads();
    for (int p = threadIdx.x; p < 1024; p += 256) {
        const int f = p >> 6, o = p & 63;
        const int v = idx[b * 16 + f];
        const float* wp = w + (size_t)v * 32768 + o;
        const float* bp = bias + v * 512;
        float s = 0.f;
        for (int d = 0; d < 512; ++d)
            s += (xr[d] + bp[d]) * wp[(size_t)d * 64];
        out[(size_t)(b * 1024 + n) * 1024 + p] = s;
    }
}

extern "C" void kernel_launch(void* const* d_in, const int* in_sizes, int n_in,
                              void* d_out, int out_size, void* d_ws, size_t ws_size,
                              hipStream_t stream) {
    const float* x    = (const float*)d_in[0];  // [4,1024,512]
    const int*   idx  = (const int*)d_in[1];    // [4,16]
    const float* bias = (const float*)d_in[2];  // [64,512]
    const float* w    = (const float*)d_in[3];  // [64,512,64]
    float* out = (float*)d_out;                 // [4,1024,16,64]

    const size_t cv_bytes = 64 * 64 * sizeof(float);      // 16 KB
    const size_t wt_bytes = (size_t)64 * 64 * 512 * 2;    // 4 MB
    const size_t xb_bytes = (size_t)4096 * 512 * 2;       // 4 MB
    if (ws_size >= cv_bytes + wt_bytes + xb_bytes) {
        float*  cv = (float*)d_ws;
        bf16_t* wt = (bf16_t*)((char*)d_ws + cv_bytes);
        bf16_t* xb = (bf16_t*)((char*)d_ws + cv_bytes + wt_bytes);
        prep_kernel<<<1088, 256, 0, stream>>>(w, bias, x, wt, cv, xb);
        gemm_kernel<<<512, 256, 0, stream>>>(xb, wt, cv, idx, out);
    } else {
        naive_kernel<<<4096, 256, 0, stream>>>(x, w, bias, idx, out);
    }
}

// Round 3
// 89.959 us; speedup vs baseline: 1.0667x; 1.0667x over previous
//
#include <hip/hip_runtime.h>
#include <hip/hip_bf16.h>
#include <stdint.h>

// Problem: B=4, N=1024, D=512, F=16, O=64, V=64. fp32 tensors, int32 idx.
// out[b,n,f,o] = sum_d (x[b,n,d]+bias[v,d])*W[v,d,o], v=idx[b,f]
//             = (x[b] @ W[v])[n,o] + c[v][o],  c[v][o]=sum_d bias[v,d]*W[v,d,o]
// prep: W -> bf16 Wt[v][o][d] + c[v] (fp32); x -> bf16.  gemm: MFMA bf16,
// fp32 accumulate, +c[v] epilogue. R2 passed absmax 0.031 (thr 0.145).
// R3: XOR-swizzled LDS (kills 8-way conflicts), BK=64 (8 iters), XCD-aware
// block order (A-tile L2 reuse), pipelined prep, 3 blocks/CU.

typedef __bf16 bf16_t;
typedef __bf16 bf16x8 __attribute__((ext_vector_type(8)));
typedef float floatx4 __attribute__((ext_vector_type(4)));

__device__ __forceinline__ void async_ld16(const bf16_t* g, bf16_t* l) {
    __builtin_amdgcn_global_load_lds(
        (const __attribute__((address_space(1))) void*)g,
        (__attribute__((address_space(3))) void*)l,
        16, 0, 0);
}

// ---------------------------------------------------------------------------
// Prep: blocks [0,64): per-v W transpose fp32->bf16 Wt[v][o][d] + c[v][o].
//       blocks [64,1088): x fp32 -> bf16 (2048 elements per block).
// W-part software-pipelined: chunk c+1 loads to regs during chunk c transpose.
// ---------------------------------------------------------------------------
__global__ __launch_bounds__(256) void prep_kernel(
    const float* __restrict__ w,     // [64][512][64]
    const float* __restrict__ bias,  // [64][512]
    const float* __restrict__ x,     // [4096][512]
    bf16_t* __restrict__ wt,         // [64][64][512]
    float* __restrict__ cv,          // [64][64]
    bf16_t* __restrict__ xb)         // [4096][512]
{
    const int t = threadIdx.x;
    if (blockIdx.x >= 64) {
        const int base = (blockIdx.x - 64) * 2048 + t * 8;
        const float4 f0 = *(const float4*)(x + base);
        const float4 f1 = *(const float4*)(x + base + 4);
        bf16x8 o;
        o[0] = (bf16_t)f0.x; o[1] = (bf16_t)f0.y;
        o[2] = (bf16_t)f0.z; o[3] = (bf16_t)f0.w;
        o[4] = (bf16_t)f1.x; o[5] = (bf16_t)f1.y;
        o[6] = (bf16_t)f1.z; o[7] = (bf16_t)f1.w;
        *(bf16x8*)(xb + base) = o;
        return;
    }

    const int v = blockIdx.x;
    __shared__ float tile[64][68];
    __shared__ float bch[64];
    __shared__ float red[4][64];

    const int r  = t >> 2, cs = (t & 3) * 16;  // load map
    const int o  = t >> 2, ds = (t & 3) * 16;  // transpose-store map
    const int dq = t >> 6, oc = t & 63;        // c-reduction map
    float csum = 0.f;
    const float* wv = w + (size_t)v * 32768;

    float4 rg0, rg1, rg2, rg3;
    {
        const float* src = wv + (size_t)r * 64 + cs;
        rg0 = *(const float4*)(src);
        rg1 = *(const float4*)(src + 4);
        rg2 = *(const float4*)(src + 8);
        rg3 = *(const float4*)(src + 12);
    }
    for (int c = 0; c < 8; ++c) {
        __syncthreads();  // consumers of previous chunk done
        *(float4*)&tile[r][cs]      = rg0;
        *(float4*)&tile[r][cs + 4]  = rg1;
        *(float4*)&tile[r][cs + 8]  = rg2;
        *(float4*)&tile[r][cs + 12] = rg3;
        if (t < 64) bch[t] = bias[v * 512 + c * 64 + t];
        __syncthreads();
        if (c < 7) {  // prefetch next chunk; overlaps transpose below
            const float* src = wv + (size_t)((c + 1) * 64 + r) * 64 + cs;
            rg0 = *(const float4*)(src);
            rg1 = *(const float4*)(src + 4);
            rg2 = *(const float4*)(src + 8);
            rg3 = *(const float4*)(src + 12);
        }
        bf16x8 t0, t1;
#pragma unroll
        for (int j = 0; j < 8; ++j) t0[j] = (bf16_t)tile[ds + j][o];
#pragma unroll
        for (int j = 0; j < 8; ++j) t1[j] = (bf16_t)tile[ds + 8 + j][o];
        bf16_t* dst = wt + ((size_t)v * 64 + o) * 512 + c * 64 + ds;
        *(bf16x8*)&dst[0] = t0;
        *(bf16x8*)&dst[8] = t1;
#pragma unroll
        for (int j = 0; j < 16; ++j) {
            const int dl = dq * 16 + j;
            csum += bch[dl] * tile[dl][oc];
        }
    }
    red[dq][oc] = csum;
    __syncthreads();
    if (t < 64) cv[v * 64 + t] = red[0][t] + red[1][t] + red[2][t] + red[3][t];
}

// ---------------------------------------------------------------------------
// GEMM: BM=128, BN=64, BK=64, 256 threads = 4 waves (each 64x32 = 4x2 frags,
// 2 k-sub MFMAs). XOR-swizzled LDS: slot = k8 ^ (row&7) -> 2-way banks (free).
// Block order: bid = f*32 + b*8 + mt  =>  16 f-blocks of one (b,mt) share
// bid mod 8 -> same XCD -> A-tile L2 reuse.
// ---------------------------------------------------------------------------
__global__ __launch_bounds__(256, 3) void gemm_kernel(
    const bf16_t* __restrict__ xb,   // [4096][512]
    const bf16_t* __restrict__ wt,   // [64][64][512]
    const float*  __restrict__ cv,   // [64][64]
    const int*    __restrict__ idx,  // [4][16]
    float* __restrict__ out)         // [4096][1024], col = f*64+o
{
    const int bid = blockIdx.x;
    const int f  = bid >> 5;
    const int b  = (bid >> 3) & 3;
    const int mt = bid & 7;
    const int v  = idx[b * 16 + f];

    const int tid  = threadIdx.x;
    const int lane = tid & 63;
    const int wave = tid >> 6;
    const int wm = wave >> 1;
    const int wn = wave & 1;
    const int l15 = lane & 15;
    const int l4  = lane >> 4;

    const bf16_t* Ag = xb + (size_t)(b * 1024 + mt * 128) * 512;  // [128][512]
    const bf16_t* Bg = wt + (size_t)v * 64 * 512;                 // [64][512]

    __shared__ __align__(16) bf16_t As[2][128 * 64];  // 16KB each
    __shared__ __align__(16) bf16_t Bs[2][64 * 64];   // 8KB each

    floatx4 acc[4][2] = {};

    // Staging: seg s -> LDS 16B slot s (lane-contiguous). A: s=tid+256j
    // (j=0..3), row=s>>3, lds slot=s&7 holds global k8 = (s&7)^(row&7).
    int a_row[4], a_col[4];
#pragma unroll
    for (int j = 0; j < 4; ++j) {
        const int s = tid + 256 * j;
        a_row[j] = s >> 3;
        a_col[j] = ((s & 7) ^ (a_row[j] & 7)) * 8;
    }
    int b_row[2], b_col[2];
#pragma unroll
    for (int j = 0; j < 2; ++j) {
        const int s = tid + 256 * j;
        b_row[j] = s >> 3;
        b_col[j] = ((s & 7) ^ (b_row[j] & 7)) * 8;
    }

#pragma unroll
    for (int j = 0; j < 4; ++j)
        async_ld16(Ag + a_row[j] * 512 + a_col[j], &As[0][(tid + 256 * j) * 8]);
#pragma unroll
    for (int j = 0; j < 2; ++j)
        async_ld16(Bg + b_row[j] * 512 + b_col[j], &Bs[0][(tid + 256 * j) * 8]);

    for (int kk = 0; kk < 8; ++kk) {
        const int buf = kk & 1;
        __syncthreads();  // drains vmcnt: buf ready; reads of buf^1 complete
        if (kk < 7) {
            const int k0 = (kk + 1) * 64;
#pragma unroll
            for (int j = 0; j < 4; ++j)
                async_ld16(Ag + a_row[j] * 512 + k0 + a_col[j],
                           &As[buf ^ 1][(tid + 256 * j) * 8]);
#pragma unroll
            for (int j = 0; j < 2; ++j)
                async_ld16(Bg + b_row[j] * 512 + k0 + b_col[j],
                           &Bs[buf ^ 1][(tid + 256 * j) * 8]);
        }
        bf16x8 a[4][2], bb[2][2];
#pragma unroll
        for (int mi = 0; mi < 4; ++mi) {
            const int row = wm * 64 + mi * 16 + l15;
#pragma unroll
            for (int ks = 0; ks < 2; ++ks)
                a[mi][ks] = *(const bf16x8*)
                    &As[buf][row * 64 + (((ks * 4 + l4) ^ (row & 7)) * 8)];
        }
#pragma unroll
        for (int ni = 0; ni < 2; ++ni) {
            const int row = wn * 32 + ni * 16 + l15;
#pragma unroll
            for (int ks = 0; ks < 2; ++ks)
                bb[ni][ks] = *(const bf16x8*)
                    &Bs[buf][row * 64 + (((ks * 4 + l4) ^ (row & 7)) * 8)];
        }
#pragma unroll
        for (int mi = 0; mi < 4; ++mi)
#pragma unroll
            for (int ni = 0; ni < 2; ++ni) {
                acc[mi][ni] = __builtin_amdgcn_mfma_f32_16x16x32_bf16(
                    a[mi][0], bb[ni][0], acc[mi][ni], 0, 0, 0);
                acc[mi][ni] = __builtin_amdgcn_mfma_f32_16x16x32_bf16(
                    a[mi][1], bb[ni][1], acc[mi][ni], 0, 0, 0);
            }
    }

    // Epilogue: C layout col = lane&15, row = (lane>>4)*4 + r. fp32 + c[v].
    const int colbase = wn * 32 + l15;
    const float c0 = cv[v * 64 + colbase];
    const float c1 = cv[v * 64 + colbase + 16];
    float* outp = out + (size_t)(b * 1024 + mt * 128 + wm * 64 + l4 * 4) * 1024
                      + f * 64;
#pragma unroll
    for (int mi = 0; mi < 4; ++mi) {
#pragma unroll
        for (int r = 0; r < 4; ++r) {
            float* row = outp + (size_t)(mi * 16 + r) * 1024;
            row[colbase]      = acc[mi][0][r] + c0;
            row[colbase + 16] = acc[mi][1][r] + c1;
        }
    }
}

// ---------------------------------------------------------------------------
// Fallback (ws too small): direct fp32, slow but correct.
// ---------------------------------------------------------------------------
__global__ __launch_bounds__(256) void naive_kernel(
    const float* __restrict__ x, const float* __restrict__ w,
    const float* __restrict__ bias, const int* __restrict__ idx,
    float* __restrict__ out)
{
    const int b = blockIdx.x >> 10;
    const int n = blockIdx.x & 1023;
    __shared__ float xr[512];
    for (int d = threadIdx.x; d < 512; d += 256)
        xr[d] = x[(size_t)(b * 1024 + n) * 512 + d];
    __syncthreads();
    for (int p = threadIdx.x; p < 1024; p += 256) {
        const int f = p >> 6, o = p & 63;
        const int v = idx[b * 16 + f];
        const float* wp = w + (size_t)v * 32768 + o;
        const float* bp = bias + v * 512;
        float s = 0.f;
        for (int d = 0; d < 512; ++d)
            s += (xr[d] + bp[d]) * wp[(size_t)d * 64];
        out[(size_t)(b * 1024 + n) * 1024 + p] = s;
    }
}

extern "C" void kernel_launch(void* const* d_in, const int* in_sizes, int n_in,
                              void* d_out, int out_size, void* d_ws, size_t ws_size,
                              hipStream_t stream) {
    const float* x    = (const float*)d_in[0];  // [4,1024,512]
    const int*   idx  = (const int*)d_in[1];    // [4,16]
    const float* bias = (const float*)d_in[2];  // [64,512]
    const float* w    = (const float*)d_in[3];  // [64,512,64]
    float* out = (float*)d_out;                 // [4,1024,16,64]

    const size_t cv_bytes = 64 * 64 * sizeof(float);      // 16 KB
    const size_t wt_bytes = (size_t)64 * 64 * 512 * 2;    // 4 MB
    const size_t xb_bytes = (size_t)4096 * 512 * 2;       // 4 MB
    if (ws_size >= cv_bytes + wt_bytes + xb_bytes) {
        float*  cv = (float*)d_ws;
        bf16_t* wt = (bf16_t*)((char*)d_ws + cv_bytes);
        bf16_t* xb = (bf16_t*)((char*)d_ws + cv_bytes + wt_bytes);
        prep_kernel<<<1088, 256, 0, stream>>>(w, bias, x, wt, cv, xb);
        gemm_kernel<<<512, 256, 0, stream>>>(xb, wt, cv, idx, out);
    } else {
        naive_kernel<<<4096, 256, 0, stream>>>(x, w, bias, idx, out);
    }
}